// Round 3
// baseline (166.715 us; speedup 1.0000x reference)
//
#include <hip/hip_runtime.h>
#include <hip/hip_bf16.h>

// Problem constants
#define BB 96    // batch
#define HH 100   // history length
#define NN 128   // candidates (broadcast only)
#define DD 768   // embed dim
#define AA 256   // attention dim

// ---------------------------------------------------------------------------
// K1: partial means of hist[:, :96, :] -> neighp[4][B][D] (4 h-groups of 24)
// ---------------------------------------------------------------------------
__global__ void k_neigh(const float* __restrict__ hist, float* __restrict__ neighp) {
  int b = blockIdx.x, hg = blockIdx.y;
  int t = threadIdx.x;
  if (t >= 192) return;  // 192 float4 = 768 floats
  const float* hb = hist + (size_t)b * HH * DD + (size_t)hg * 24 * DD + t * 4;
  float4 acc = make_float4(0.f, 0.f, 0.f, 0.f);
#pragma unroll 8
  for (int i = 0; i < 24; ++i) {
    float4 x = *(const float4*)(hb + (size_t)i * DD);
    acc.x += x.x; acc.y += x.y; acc.z += x.z; acc.w += x.w;
  }
  *(float4*)(neighp + ((size_t)hg * BB + b) * DD + t * 4) = acc;
}

// ---------------------------------------------------------------------------
// K2: nl[b,e] = neigh[b,:]·W_l[e,:] + b_l[e] ;  u0[b,e] = hist[b,0,:]·W_r[e,:] + nl[b,e]
// wave-split-K shuffle reduce, 4 batches per block, 32 e per block
// ---------------------------------------------------------------------------
__global__ void k_nl_u0(const float* __restrict__ neighp, const float* __restrict__ hist,
                        const float* __restrict__ Wl, const float* __restrict__ bl,
                        const float* __restrict__ Wr,
                        float* __restrict__ nl, float* __restrict__ u0) {
  int e0 = blockIdx.x * 32;
  int b0 = blockIdx.y * 4;
  int lane = threadIdx.x & 63, wave = threadIdx.x >> 6;
  float xn[4][12], xh[4][12];
#pragma unroll
  for (int bi = 0; bi < 4; ++bi) {
    int b = b0 + bi;
    const float* hb = hist + (size_t)b * HH * DD;  // h = 0 row
#pragma unroll
    for (int j = 0; j < 12; ++j) {
      int idx = lane + 64 * j;
      xn[bi][j] = (neighp[(0 * BB + b) * DD + idx] + neighp[(1 * BB + b) * DD + idx] +
                   neighp[(2 * BB + b) * DD + idx] + neighp[(3 * BB + b) * DD + idx]) * (1.f / 96.f);
      xh[bi][j] = hb[idx];
    }
  }
  for (int i = 0; i < 8; ++i) {
    int e = e0 + wave * 8 + i;
    const float* wl = Wl + (size_t)e * DD;
    const float* wr = Wr + (size_t)e * DD;
    float w[12];
#pragma unroll
    for (int j = 0; j < 12; ++j) w[j] = wl[lane + 64 * j];
    float p[4] = {0.f, 0.f, 0.f, 0.f};
#pragma unroll
    for (int j = 0; j < 12; ++j)
#pragma unroll
      for (int bi = 0; bi < 4; ++bi) p[bi] += w[j] * xn[bi][j];
#pragma unroll
    for (int j = 0; j < 12; ++j) w[j] = wr[lane + 64 * j];
    float q[4] = {0.f, 0.f, 0.f, 0.f};
#pragma unroll
    for (int j = 0; j < 12; ++j)
#pragma unroll
      for (int bi = 0; bi < 4; ++bi) q[bi] += w[j] * xh[bi][j];
#pragma unroll
    for (int bi = 0; bi < 4; ++bi) {
      float pp = p[bi], qq = q[bi];
      for (int off = 32; off; off >>= 1) {
        pp += __shfl_down(pp, off, 64);
        qq += __shfl_down(qq, off, 64);
      }
      if (lane == 0) {
        float nle = pp + bl[e];
        nl[(size_t)(b0 + bi) * DD + e] = nle;
        u0[(size_t)(b0 + bi) * DD + e] = qq + nle;
      }
    }
  }
}

// ---------------------------------------------------------------------------
// K3: Q[b,a] = u0[b,:]·W_Q[a,:] + b_Q[a]   (E=256, K=768), same pattern
// ---------------------------------------------------------------------------
__global__ void k_q(const float* __restrict__ u0, const float* __restrict__ WQ,
                    const float* __restrict__ bQ, float* __restrict__ Qm) {
  int e0 = blockIdx.x * 32;
  int b0 = blockIdx.y * 4;
  int lane = threadIdx.x & 63, wave = threadIdx.x >> 6;
  float x[4][12];
#pragma unroll
  for (int bi = 0; bi < 4; ++bi) {
    const float* xb = u0 + (size_t)(b0 + bi) * DD;
#pragma unroll
    for (int j = 0; j < 12; ++j) x[bi][j] = xb[lane + 64 * j];
  }
  for (int i = 0; i < 8; ++i) {
    int e = e0 + wave * 8 + i;
    const float* w = WQ + (size_t)e * DD;
    float wr[12];
#pragma unroll
    for (int j = 0; j < 12; ++j) wr[j] = w[lane + 64 * j];
    float p[4] = {0.f, 0.f, 0.f, 0.f};
#pragma unroll
    for (int j = 0; j < 12; ++j)
#pragma unroll
      for (int bi = 0; bi < 4; ++bi) p[bi] += wr[j] * x[bi][j];
#pragma unroll
    for (int bi = 0; bi < 4; ++bi) {
      float pp = p[bi];
      for (int off = 32; off; off >>= 1) pp += __shfl_down(pp, off, 64);
      if (lane == 0) Qm[(size_t)(b0 + bi) * AA + e] = pp + bQ[e];
    }
  }
}

// ---------------------------------------------------------------------------
// K4: qk[b,d] = sum_a Q[b,a] * W_K[a,d]   (coalesced thread-per-d, 4 b/thread)
// ---------------------------------------------------------------------------
__global__ void k_qk(const float* __restrict__ Qm, const float* __restrict__ WK,
                     float* __restrict__ qk) {
  int d = blockIdx.x * 256 + threadIdx.x;
  int b0 = blockIdx.y * 4;
  float a0 = 0.f, a1 = 0.f, a2 = 0.f, a3 = 0.f;
  for (int a = 0; a < AA; ++a) {
    float w = WK[(size_t)a * DD + d];
    a0 += Qm[(size_t)(b0 + 0) * AA + a] * w;
    a1 += Qm[(size_t)(b0 + 1) * AA + a] * w;
    a2 += Qm[(size_t)(b0 + 2) * AA + a] * w;
    a3 += Qm[(size_t)(b0 + 3) * AA + a] * w;
  }
  qk[(size_t)(b0 + 0) * DD + d] = a0;
  qk[(size_t)(b0 + 1) * DD + d] = a1;
  qk[(size_t)(b0 + 2) * DD + d] = a2;
  qk[(size_t)(b0 + 3) * DD + d] = a3;
}

// ---------------------------------------------------------------------------
// K5: v[b,e] = (1/16) * sum_d qk[b,d] * W_r[d,e]   (1/sqrt(A) folded in)
// ---------------------------------------------------------------------------
__global__ void k_v(const float* __restrict__ qk, const float* __restrict__ Wr,
                    float* __restrict__ vv) {
  int e = blockIdx.x * 256 + threadIdx.x;
  int b0 = blockIdx.y * 2;
  float a0 = 0.f, a1 = 0.f;
  for (int d = 0; d < DD; ++d) {
    float w = Wr[(size_t)d * DD + e];
    a0 += qk[(size_t)(b0 + 0) * DD + d] * w;
    a1 += qk[(size_t)(b0 + 1) * DD + d] * w;
  }
  vv[(size_t)(b0 + 0) * DD + e] = a0 * (1.f / 16.f);
  vv[(size_t)(b0 + 1) * DD + e] = a1 * (1.f / 16.f);
}

// ---------------------------------------------------------------------------
// K6: scores[b,h] = hist[b,h,:]·v[b,:]   (wave-split-K; 20 h per block)
// ---------------------------------------------------------------------------
__global__ void k_scores(const float* __restrict__ hist, const float* __restrict__ vv,
                         float* __restrict__ sc) {
  int b = blockIdx.x, hg = blockIdx.y;
  int lane = threadIdx.x & 63, wave = threadIdx.x >> 6;
  float v[12];
  const float* vb = vv + (size_t)b * DD;
#pragma unroll
  for (int j = 0; j < 12; ++j) v[j] = vb[lane + 64 * j];
  const float* hb = hist + (size_t)b * HH * DD;
  for (int i = 0; i < 5; ++i) {
    int h = hg * 20 + wave * 5 + i;
    const float* r = hb + (size_t)h * DD;
    float p = 0.f;
#pragma unroll
    for (int j = 0; j < 12; ++j) p += r[lane + 64 * j] * v[j];
    for (int off = 32; off; off >>= 1) p += __shfl_down(p, off, 64);
    if (lane == 0) sc[b * 128 + h] = p;
  }
}

// ---------------------------------------------------------------------------
// K7: softmax over h (recomputed redundantly per block) + wsum[b,e] = sum_h alpha*hist
// ---------------------------------------------------------------------------
__global__ void k_wsum(const float* __restrict__ hist, const float* __restrict__ sc,
                       float* __restrict__ wsum) {
  int b = blockIdx.x;
  int e = blockIdx.y * 256 + threadIdx.x;
  __shared__ float sh[HH];
  if (threadIdx.x < HH) sh[threadIdx.x] = sc[b * 128 + threadIdx.x];
  __syncthreads();
  float m = -1e30f;
  for (int h = 0; h < HH; ++h) m = fmaxf(m, sh[h]);
  float s = 0.f;
  for (int h = 0; h < HH; ++h) s += __expf(sh[h] - m);
  float inv = 1.f / s;
  float acc = 0.f;
  const float* hb = hist + (size_t)b * HH * DD + e;
  for (int h = 0; h < HH; ++h) {
    float al = __expf(sh[h] - m) * inv;
    acc += al * hb[(size_t)h * DD];
  }
  wsum[(size_t)b * DD + e] = acc;
}

// ---------------------------------------------------------------------------
// K8: orow[b,d] = nl[b,d] + sum_e wsum[b,e] * W_r[d,e]
// ---------------------------------------------------------------------------
__global__ void k_orow(const float* __restrict__ wsum, const float* __restrict__ Wr,
                       const float* __restrict__ nl, float* __restrict__ orow) {
  int d0 = blockIdx.x * 32;
  int b0 = blockIdx.y * 4;
  int lane = threadIdx.x & 63, wave = threadIdx.x >> 6;
  float x[4][12];
#pragma unroll
  for (int bi = 0; bi < 4; ++bi) {
    const float* xb = wsum + (size_t)(b0 + bi) * DD;
#pragma unroll
    for (int j = 0; j < 12; ++j) x[bi][j] = xb[lane + 64 * j];
  }
  for (int i = 0; i < 8; ++i) {
    int d = d0 + wave * 8 + i;
    const float* w = Wr + (size_t)d * DD;
    float wr[12];
#pragma unroll
    for (int j = 0; j < 12; ++j) wr[j] = w[lane + 64 * j];
    float p[4] = {0.f, 0.f, 0.f, 0.f};
#pragma unroll
    for (int j = 0; j < 12; ++j)
#pragma unroll
      for (int bi = 0; bi < 4; ++bi) p[bi] += wr[j] * x[bi][j];
#pragma unroll
    for (int bi = 0; bi < 4; ++bi) {
      float pp = p[bi];
      for (int off = 32; off; off >>= 1) pp += __shfl_down(pp, off, 64);
      if (lane == 0)
        orow[(size_t)(b0 + bi) * DD + d] = pp + nl[(size_t)(b0 + bi) * DD + d];
    }
  }
}

// ---------------------------------------------------------------------------
// K9: out[b,n,d] = orow[b,d]  — FLOAT32 output (reference returns float32),
// float4 per thread, fully coalesced.
// ---------------------------------------------------------------------------
__global__ void k_write(const float* __restrict__ orow, float* __restrict__ out) {
  size_t t = (size_t)blockIdx.x * 256 + threadIdx.x;  // 2,359,296 threads
  int d4 = (int)(t % (DD / 4));                       // 0..191
  int bn = (int)(t / (DD / 4));                       // b*128 + n
  int b = bn >> 7;
  float4 v = *(const float4*)(orow + (size_t)b * DD + d4 * 4);
  *(float4*)(out + (size_t)bn * DD + d4 * 4) = v;
}

// ---------------------------------------------------------------------------
extern "C" void kernel_launch(void* const* d_in, const int* in_sizes, int n_in,
                              void* d_out, int out_size, void* d_ws, size_t ws_size,
                              hipStream_t stream) {
  // Size-based input identification — robust to input-ordering conventions.
  // (Under dict order this matches: hist, cand, W_l, b_l, W_r, W_K, W_Q, b_Q.)
  const float *hist = nullptr, *Wl = nullptr, *Wr = nullptr, *WK = nullptr,
              *WQ = nullptr, *bl = nullptr, *bQ = nullptr;
  int seenDxD = 0, seenAxD = 0;
  for (int i = 0; i < n_in; ++i) {
    int s = in_sizes[i];
    const float* p = (const float*)d_in[i];
    if (s == BB * HH * DD) hist = p;                              // 7,372,800
    else if (s == BB * NN * DD) { /* candidate — unused */ }      // 9,437,184
    else if (s == DD * DD) { if (seenDxD++ == 0) Wl = p; else Wr = p; }  // 589,824
    else if (s == AA * DD) { if (seenAxD++ == 0) WK = p; else WQ = p; }  // 196,608
    else if (s == DD) bl = p;                                      // 768
    else if (s == AA) bQ = p;                                      // 256
  }

  float* ws = (float*)d_ws;
  // float offsets (all multiples of 16 -> 64B aligned); total ~3.1 MB
  float* neighp = ws + 0;        // 4*96*768 = 294912
  float* nl     = ws + 294912;   // 73728
  float* u0     = ws + 368640;   // 73728
  float* Qm     = ws + 442368;   // 24576
  float* qk     = ws + 466944;   // 73728
  float* vv     = ws + 540672;   // 73728
  float* sc     = ws + 614400;   // 96*128 = 12288
  float* wsum   = ws + 626688;   // 73728
  float* orow   = ws + 700416;   // 73728
  float* out = (float*)d_out;

  k_neigh <<<dim3(BB, 4),  dim3(256), 0, stream>>>(hist, neighp);
  k_nl_u0 <<<dim3(24, 24), dim3(256), 0, stream>>>(neighp, hist, Wl, bl, Wr, nl, u0);
  k_q     <<<dim3(8, 24),  dim3(256), 0, stream>>>(u0, WQ, bQ, Qm);
  k_qk    <<<dim3(3, 24),  dim3(256), 0, stream>>>(Qm, WK, qk);
  k_v     <<<dim3(3, 48),  dim3(256), 0, stream>>>(qk, Wr, vv);
  k_scores<<<dim3(BB, 5),  dim3(256), 0, stream>>>(hist, vv, sc);
  k_wsum  <<<dim3(BB, 3),  dim3(256), 0, stream>>>(hist, sc, wsum);
  k_orow  <<<dim3(24, 24), dim3(256), 0, stream>>>(wsum, Wr, nl, orow);
  k_write <<<dim3(9216),   dim3(256), 0, stream>>>(orow, out);
}

// Round 4
// 165.576 us; speedup vs baseline: 1.0069x; 1.0069x over previous
//
#include <hip/hip_runtime.h>
#include <hip/hip_bf16.h>

// Problem constants
#define BB 96    // batch
#define HH 100   // history length
#define NN 128   // candidates (broadcast only)
#define DD 768   // embed dim
#define AA 256   // attention dim

static __device__ __forceinline__ float dot4(float4 a, float4 b) {
  return a.x * b.x + a.y * b.y + a.z * b.z + a.w * b.w;
}

// ---------------------------------------------------------------------------
// K1: partial means of hist[:, :96, :] -> neighp[4][B][D] (4 h-groups of 24)
// ---------------------------------------------------------------------------
__global__ void k_neigh(const float* __restrict__ hist, float* __restrict__ neighp) {
  int b = blockIdx.x, hg = blockIdx.y;
  int t = threadIdx.x;  // block = 192 threads, 192 float4 = 768 floats
  const float* hb = hist + (size_t)b * HH * DD + (size_t)hg * 24 * DD + t * 4;
  float4 acc = make_float4(0.f, 0.f, 0.f, 0.f);
#pragma unroll 8
  for (int i = 0; i < 24; ++i) {
    float4 x = *(const float4*)(hb + (size_t)i * DD);
    acc.x += x.x; acc.y += x.y; acc.z += x.z; acc.w += x.w;
  }
  *(float4*)(neighp + ((size_t)hg * BB + b) * DD + t * 4) = acc;
}

// ---------------------------------------------------------------------------
// K2: nl[b,e] = neigh[b,:]·W_l[e,:] + b_l[e] ;  u0[b,e] = hist[b,0,:]·W_r[e,:] + nl[b,e]
// wave-split-K, 3 batches per thread (float4 fragments, no spill), 32 e per block
// grid (24 e-tiles, 32 b-groups)
// ---------------------------------------------------------------------------
__global__ void k_nl_u0(const float* __restrict__ neighp, const float* __restrict__ hist,
                        const float* __restrict__ Wl, const float* __restrict__ bl,
                        const float* __restrict__ Wr,
                        float* __restrict__ nl, float* __restrict__ u0) {
  int e0 = blockIdx.x * 32;
  int b0 = blockIdx.y * 3;
  int lane = threadIdx.x & 63, wave = threadIdx.x >> 6;
  float4 xn[3][3], xh[3][3];
#pragma unroll
  for (int bi = 0; bi < 3; ++bi) {
    int b = b0 + bi;
#pragma unroll
    for (int jj = 0; jj < 3; ++jj) {
      int idx = lane + 64 * jj;  // float4 index within 768-float row
      float4 s0 = ((const float4*)(neighp + ((size_t)0 * BB + b) * DD))[idx];
      float4 s1 = ((const float4*)(neighp + ((size_t)1 * BB + b) * DD))[idx];
      float4 s2 = ((const float4*)(neighp + ((size_t)2 * BB + b) * DD))[idx];
      float4 s3 = ((const float4*)(neighp + ((size_t)3 * BB + b) * DD))[idx];
      xn[bi][jj] = make_float4((s0.x + s1.x + s2.x + s3.x) * (1.f / 96.f),
                               (s0.y + s1.y + s2.y + s3.y) * (1.f / 96.f),
                               (s0.z + s1.z + s2.z + s3.z) * (1.f / 96.f),
                               (s0.w + s1.w + s2.w + s3.w) * (1.f / 96.f));
      xh[bi][jj] = ((const float4*)(hist + (size_t)b * HH * DD))[idx];  // h = 0 row
    }
  }
  for (int i = 0; i < 8; ++i) {
    int e = e0 + wave * 8 + i;
    const float4* wl4 = (const float4*)(Wl + (size_t)e * DD);
    const float4* wr4 = (const float4*)(Wr + (size_t)e * DD);
    float pl[3] = {0.f, 0.f, 0.f}, pr[3] = {0.f, 0.f, 0.f};
#pragma unroll
    for (int jj = 0; jj < 3; ++jj) {
      float4 wl = wl4[lane + 64 * jj];
      float4 wr = wr4[lane + 64 * jj];
#pragma unroll
      for (int bi = 0; bi < 3; ++bi) {
        pl[bi] += dot4(wl, xn[bi][jj]);
        pr[bi] += dot4(wr, xh[bi][jj]);
      }
    }
#pragma unroll
    for (int bi = 0; bi < 3; ++bi) {
      float pp = pl[bi], qq = pr[bi];
      for (int off = 32; off; off >>= 1) {
        pp += __shfl_down(pp, off, 64);
        qq += __shfl_down(qq, off, 64);
      }
      if (lane == 0) {
        float nle = pp + bl[e];
        nl[(size_t)(b0 + bi) * DD + e] = nle;
        u0[(size_t)(b0 + bi) * DD + e] = qq + nle;
      }
    }
  }
}

// ---------------------------------------------------------------------------
// K3: Q[b,a] = u0[b,:]·W_Q[a,:] + b_Q[a]   grid (8 a-tiles, 32 b-groups)
// ---------------------------------------------------------------------------
__global__ void k_q(const float* __restrict__ u0, const float* __restrict__ WQ,
                    const float* __restrict__ bQ, float* __restrict__ Qm) {
  int a0 = blockIdx.x * 32;
  int b0 = blockIdx.y * 3;
  int lane = threadIdx.x & 63, wave = threadIdx.x >> 6;
  float4 x[3][3];
#pragma unroll
  for (int bi = 0; bi < 3; ++bi)
#pragma unroll
    for (int jj = 0; jj < 3; ++jj)
      x[bi][jj] = ((const float4*)(u0 + (size_t)(b0 + bi) * DD))[lane + 64 * jj];
  for (int i = 0; i < 8; ++i) {
    int a = a0 + wave * 8 + i;
    const float4* w4 = (const float4*)(WQ + (size_t)a * DD);
    float p[3] = {0.f, 0.f, 0.f};
#pragma unroll
    for (int jj = 0; jj < 3; ++jj) {
      float4 w = w4[lane + 64 * jj];
#pragma unroll
      for (int bi = 0; bi < 3; ++bi) p[bi] += dot4(w, x[bi][jj]);
    }
#pragma unroll
    for (int bi = 0; bi < 3; ++bi) {
      float pp = p[bi];
      for (int off = 32; off; off >>= 1) pp += __shfl_down(pp, off, 64);
      if (lane == 0) Qm[(size_t)(b0 + bi) * AA + a] = pp + bQ[a];
    }
  }
}

// ---------------------------------------------------------------------------
// K4: qk[b,d] = sum_a Q[b,a] * W_K[a,d]   (thread-per-d, Q staged in LDS)
// grid (3 d-tiles, 24 b-groups)
// ---------------------------------------------------------------------------
__global__ void k_qk(const float* __restrict__ Qm, const float* __restrict__ WK,
                     float* __restrict__ qk) {
  int b0 = blockIdx.y * 4;
  __shared__ float sQ[4 * AA];
  for (int i = threadIdx.x; i < 4 * AA; i += 256)
    sQ[i] = Qm[((size_t)b0 + (i >> 8)) * AA + (i & (AA - 1))];
  __syncthreads();
  int d = blockIdx.x * 256 + threadIdx.x;
  float a0 = 0.f, a1 = 0.f, a2 = 0.f, a3 = 0.f;
#pragma unroll 4
  for (int a = 0; a < AA; ++a) {
    float w = WK[(size_t)a * DD + d];
    a0 += sQ[0 * AA + a] * w;
    a1 += sQ[1 * AA + a] * w;
    a2 += sQ[2 * AA + a] * w;
    a3 += sQ[3 * AA + a] * w;
  }
  qk[(size_t)(b0 + 0) * DD + d] = a0;
  qk[(size_t)(b0 + 1) * DD + d] = a1;
  qk[(size_t)(b0 + 2) * DD + d] = a2;
  qk[(size_t)(b0 + 3) * DD + d] = a3;
}

// ---------------------------------------------------------------------------
// K5: v[b,e] = (1/16) * sum_d qk[b,d] * W_r[d,e]  (qk staged in LDS)
// grid (3 e-tiles, 48 b-groups)
// ---------------------------------------------------------------------------
__global__ void k_v(const float* __restrict__ qk, const float* __restrict__ Wr,
                    float* __restrict__ vv) {
  int b0 = blockIdx.y * 2;
  __shared__ float sq[2 * DD];
  for (int i = threadIdx.x; i < 2 * DD; i += 256)
    sq[i] = qk[((size_t)b0 + (i >= DD ? 1 : 0)) * DD + (i >= DD ? i - DD : i)];
  __syncthreads();
  int e = blockIdx.x * 256 + threadIdx.x;
  float a0 = 0.f, a1 = 0.f;
#pragma unroll 4
  for (int d = 0; d < DD; ++d) {
    float w = Wr[(size_t)d * DD + e];
    a0 += sq[d] * w;
    a1 += sq[DD + d] * w;
  }
  vv[(size_t)(b0 + 0) * DD + e] = a0 * (1.f / 16.f);
  vv[(size_t)(b0 + 1) * DD + e] = a1 * (1.f / 16.f);
}

// ---------------------------------------------------------------------------
// K6: scores[b,h] = hist[b,h,:]·v[b,:]   (wave-split-K; 20 h per block)
// ---------------------------------------------------------------------------
__global__ void k_scores(const float* __restrict__ hist, const float* __restrict__ vv,
                         float* __restrict__ sc) {
  int b = blockIdx.x, hg = blockIdx.y;
  int lane = threadIdx.x & 63, wave = threadIdx.x >> 6;
  float4 v[3];
  const float4* vb = (const float4*)(vv + (size_t)b * DD);
#pragma unroll
  for (int jj = 0; jj < 3; ++jj) v[jj] = vb[lane + 64 * jj];
  const float* hb = hist + (size_t)b * HH * DD;
  for (int i = 0; i < 5; ++i) {
    int h = hg * 20 + wave * 5 + i;
    const float4* r = (const float4*)(hb + (size_t)h * DD);
    float p = 0.f;
#pragma unroll
    for (int jj = 0; jj < 3; ++jj) p += dot4(r[lane + 64 * jj], v[jj]);
    for (int off = 32; off; off >>= 1) p += __shfl_down(p, off, 64);
    if (lane == 0) sc[b * 128 + h] = p;
  }
}

// ---------------------------------------------------------------------------
// K7: softmax over h (alpha computed once per block in LDS) + weighted hist sum
// ---------------------------------------------------------------------------
__global__ void k_wsum(const float* __restrict__ hist, const float* __restrict__ sc,
                       float* __restrict__ wsum) {
  int b = blockIdx.x;
  int e = blockIdx.y * 256 + threadIdx.x;
  __shared__ float sal[HH];
  __shared__ float s_inv;
  if (threadIdx.x < HH) sal[threadIdx.x] = sc[b * 128 + threadIdx.x];
  __syncthreads();
  if (threadIdx.x == 0) {
    float m = -1e30f;
    for (int h = 0; h < HH; ++h) m = fmaxf(m, sal[h]);
    float s = 0.f;
    for (int h = 0; h < HH; ++h) { float ex = __expf(sal[h] - m); sal[h] = ex; s += ex; }
    s_inv = 1.f / s;
  }
  __syncthreads();
  float inv = s_inv;
  float acc = 0.f;
  const float* hb = hist + (size_t)b * HH * DD + e;
#pragma unroll 4
  for (int h = 0; h < HH; ++h) acc += sal[h] * hb[(size_t)h * DD];
  wsum[(size_t)b * DD + e] = acc * inv;
}

// ---------------------------------------------------------------------------
// K8: orow[b,d] = nl[b,d] + sum_e wsum[b,e] * W_r[d,e]   grid (24, 32)
// ---------------------------------------------------------------------------
__global__ void k_orow(const float* __restrict__ wsum, const float* __restrict__ Wr,
                       const float* __restrict__ nl, float* __restrict__ orow) {
  int d0 = blockIdx.x * 32;
  int b0 = blockIdx.y * 3;
  int lane = threadIdx.x & 63, wave = threadIdx.x >> 6;
  float4 x[3][3];
#pragma unroll
  for (int bi = 0; bi < 3; ++bi)
#pragma unroll
    for (int jj = 0; jj < 3; ++jj)
      x[bi][jj] = ((const float4*)(wsum + (size_t)(b0 + bi) * DD))[lane + 64 * jj];
  for (int i = 0; i < 8; ++i) {
    int d = d0 + wave * 8 + i;
    const float4* w4 = (const float4*)(Wr + (size_t)d * DD);
    float p[3] = {0.f, 0.f, 0.f};
#pragma unroll
    for (int jj = 0; jj < 3; ++jj) {
      float4 w = w4[lane + 64 * jj];
#pragma unroll
      for (int bi = 0; bi < 3; ++bi) p[bi] += dot4(w, x[bi][jj]);
    }
#pragma unroll
    for (int bi = 0; bi < 3; ++bi) {
      float pp = p[bi];
      for (int off = 32; off; off >>= 1) pp += __shfl_down(pp, off, 64);
      if (lane == 0)
        orow[(size_t)(b0 + bi) * DD + d] = pp + nl[(size_t)(b0 + bi) * DD + d];
    }
  }
}

// ---------------------------------------------------------------------------
// K9: out[b,n,d] = orow[b,d]  — float4 per thread, fully coalesced
// ---------------------------------------------------------------------------
__global__ void k_write(const float* __restrict__ orow, float* __restrict__ out) {
  size_t t = (size_t)blockIdx.x * 256 + threadIdx.x;  // 2,359,296 threads
  int d4 = (int)(t % (DD / 4));                       // 0..191
  int bn = (int)(t / (DD / 4));                       // b*128 + n
  int b = bn >> 7;
  float4 v = *(const float4*)(orow + (size_t)b * DD + d4 * 4);
  *(float4*)(out + (size_t)bn * DD + d4 * 4) = v;
}

// ---------------------------------------------------------------------------
extern "C" void kernel_launch(void* const* d_in, const int* in_sizes, int n_in,
                              void* d_out, int out_size, void* d_ws, size_t ws_size,
                              hipStream_t stream) {
  // Size-based input identification — robust to input-ordering conventions.
  const float *hist = nullptr, *Wl = nullptr, *Wr = nullptr, *WK = nullptr,
              *WQ = nullptr, *bl = nullptr, *bQ = nullptr;
  int seenDxD = 0, seenAxD = 0;
  for (int i = 0; i < n_in; ++i) {
    int s = in_sizes[i];
    const float* p = (const float*)d_in[i];
    if (s == BB * HH * DD) hist = p;                              // 7,372,800
    else if (s == BB * NN * DD) { /* candidate — unused */ }      // 9,437,184
    else if (s == DD * DD) { if (seenDxD++ == 0) Wl = p; else Wr = p; }  // 589,824
    else if (s == AA * DD) { if (seenAxD++ == 0) WK = p; else WQ = p; }  // 196,608
    else if (s == DD) bl = p;                                      // 768
    else if (s == AA) bQ = p;                                      // 256
  }

  float* ws = (float*)d_ws;
  float* neighp = ws + 0;        // 294912
  float* nl     = ws + 294912;   // 73728
  float* u0     = ws + 368640;   // 73728
  float* Qm     = ws + 442368;   // 24576
  float* qk     = ws + 466944;   // 73728
  float* vv     = ws + 540672;   // 73728
  float* sc     = ws + 614400;   // 12288
  float* wsum   = ws + 626688;   // 73728
  float* orow   = ws + 700416;   // 73728
  float* out = (float*)d_out;

  k_neigh <<<dim3(BB, 4),  dim3(192), 0, stream>>>(hist, neighp);
  k_nl_u0 <<<dim3(24, 32), dim3(256), 0, stream>>>(neighp, hist, Wl, bl, Wr, nl, u0);
  k_q     <<<dim3(8, 32),  dim3(256), 0, stream>>>(u0, WQ, bQ, Qm);
  k_qk    <<<dim3(3, 24),  dim3(256), 0, stream>>>(Qm, WK, qk);
  k_v     <<<dim3(3, 48),  dim3(256), 0, stream>>>(qk, Wr, vv);
  k_scores<<<dim3(BB, 5),  dim3(256), 0, stream>>>(hist, vv, sc);
  k_wsum  <<<dim3(BB, 3),  dim3(256), 0, stream>>>(hist, sc, wsum);
  k_orow  <<<dim3(24, 32), dim3(256), 0, stream>>>(wsum, Wr, nl, orow);
  k_write <<<dim3(9216),   dim3(256), 0, stream>>>(orow, out);
}

// Round 5
// 109.218 us; speedup vs baseline: 1.5264x; 1.5160x over previous
//
#include <hip/hip_runtime.h>
#include <hip/hip_bf16.h>

// Problem constants
#define BB 96    // batch
#define HH 100   // history length
#define NN 128   // candidates (broadcast only)
#define DD 768   // embed dim
#define AA 256   // attention dim

static __device__ __forceinline__ float dot4(float4 a, float4 b) {
  return a.x * b.x + a.y * b.y + a.z * b.z + a.w * b.w;
}

// ---------------------------------------------------------------------------
// T: LDS-tiled transpose  dst[c,r] = src[r,c]   (R, C multiples of 32)
// block 256 = 32x8, tile 32x32 (+1 pad), grid (C/32, R/32)
// ---------------------------------------------------------------------------
__global__ void t_trans(const float* __restrict__ src, float* __restrict__ dst,
                        int R, int C) {
  __shared__ float tile[32][33];
  int tx = threadIdx.x & 31, ty = threadIdx.x >> 5;
  int c0 = blockIdx.x * 32, r0 = blockIdx.y * 32;
#pragma unroll
  for (int k = 0; k < 4; ++k)
    tile[ty + 8 * k][tx] = src[(size_t)(r0 + ty + 8 * k) * C + c0 + tx];
  __syncthreads();
#pragma unroll
  for (int k = 0; k < 4; ++k)
    dst[(size_t)(c0 + ty + 8 * k) * R + r0 + tx] = tile[tx][ty + 8 * k];
}

// ---------------------------------------------------------------------------
// K1: partial means of hist[:, :96, :] -> neighp[8][B][D] (8 h-groups of 12)
// ---------------------------------------------------------------------------
__global__ void k_neigh(const float* __restrict__ hist, float* __restrict__ neighp) {
  int b = blockIdx.x, hg = blockIdx.y;
  int t = threadIdx.x;  // 192 threads * float4 = 768
  const float* hb = hist + (size_t)b * HH * DD + (size_t)hg * 12 * DD + t * 4;
  float4 acc = make_float4(0.f, 0.f, 0.f, 0.f);
#pragma unroll
  for (int i = 0; i < 12; ++i) {
    float4 x = *(const float4*)(hb + (size_t)i * DD);
    acc.x += x.x; acc.y += x.y; acc.z += x.z; acc.w += x.w;
  }
  *(float4*)(neighp + ((size_t)hg * BB + b) * DD + t * 4) = acc;
}

// ---------------------------------------------------------------------------
// K2: nl[b,e] = neigh[b,:]·W_l[e,:] + b_l[e] ;  u0[b,e] = hist[b,0,:]·W_r[e,:] + nl[b,e]
// wave-split-K, 3 b/thread, 32 e/block, grid (24, 32)
// ---------------------------------------------------------------------------
__global__ void k_nl_u0(const float* __restrict__ neighp, const float* __restrict__ hist,
                        const float* __restrict__ Wl, const float* __restrict__ bl,
                        const float* __restrict__ Wr,
                        float* __restrict__ nl, float* __restrict__ u0) {
  int e0 = blockIdx.x * 32;
  int b0 = blockIdx.y * 3;
  int lane = threadIdx.x & 63, wave = threadIdx.x >> 6;
  float4 xn[3][3], xh[3][3];
#pragma unroll
  for (int bi = 0; bi < 3; ++bi) {
    int b = b0 + bi;
#pragma unroll
    for (int jj = 0; jj < 3; ++jj) {
      int idx = lane + 64 * jj;
      float4 s = make_float4(0.f, 0.f, 0.f, 0.f);
#pragma unroll
      for (int g = 0; g < 8; ++g) {
        float4 x = ((const float4*)(neighp + ((size_t)g * BB + b) * DD))[idx];
        s.x += x.x; s.y += x.y; s.z += x.z; s.w += x.w;
      }
      xn[bi][jj] = make_float4(s.x * (1.f / 96.f), s.y * (1.f / 96.f),
                               s.z * (1.f / 96.f), s.w * (1.f / 96.f));
      xh[bi][jj] = ((const float4*)(hist + (size_t)b * HH * DD))[idx];  // h=0 row
    }
  }
  for (int i = 0; i < 8; ++i) {
    int e = e0 + wave * 8 + i;
    const float4* wl4 = (const float4*)(Wl + (size_t)e * DD);
    const float4* wr4 = (const float4*)(Wr + (size_t)e * DD);
    float pl[3] = {0.f, 0.f, 0.f}, pr[3] = {0.f, 0.f, 0.f};
#pragma unroll
    for (int jj = 0; jj < 3; ++jj) {
      float4 wl = wl4[lane + 64 * jj];
      float4 wr = wr4[lane + 64 * jj];
#pragma unroll
      for (int bi = 0; bi < 3; ++bi) {
        pl[bi] += dot4(wl, xn[bi][jj]);
        pr[bi] += dot4(wr, xh[bi][jj]);
      }
    }
#pragma unroll
    for (int bi = 0; bi < 3; ++bi) {
      float pp = pl[bi], qq = pr[bi];
      for (int off = 32; off; off >>= 1) {
        pp += __shfl_down(pp, off, 64);
        qq += __shfl_down(qq, off, 64);
      }
      if (lane == 0) {
        float nle = pp + bl[e];
        nl[(size_t)(b0 + bi) * DD + e] = nle;
        u0[(size_t)(b0 + bi) * DD + e] = qq + nle;
      }
    }
  }
}

// ---------------------------------------------------------------------------
// K3: Q[b,a] = u0[b,:]·W_Q[a,:] + b_Q[a]   grid (8, 32)
// ---------------------------------------------------------------------------
__global__ void k_q(const float* __restrict__ u0, const float* __restrict__ WQ,
                    const float* __restrict__ bQ, float* __restrict__ Qm) {
  int a0 = blockIdx.x * 32;
  int b0 = blockIdx.y * 3;
  int lane = threadIdx.x & 63, wave = threadIdx.x >> 6;
  float4 x[3][3];
#pragma unroll
  for (int bi = 0; bi < 3; ++bi)
#pragma unroll
    for (int jj = 0; jj < 3; ++jj)
      x[bi][jj] = ((const float4*)(u0 + (size_t)(b0 + bi) * DD))[lane + 64 * jj];
  for (int i = 0; i < 8; ++i) {
    int a = a0 + wave * 8 + i;
    const float4* w4 = (const float4*)(WQ + (size_t)a * DD);
    float p[3] = {0.f, 0.f, 0.f};
#pragma unroll
    for (int jj = 0; jj < 3; ++jj) {
      float4 w = w4[lane + 64 * jj];
#pragma unroll
      for (int bi = 0; bi < 3; ++bi) p[bi] += dot4(w, x[bi][jj]);
    }
#pragma unroll
    for (int bi = 0; bi < 3; ++bi) {
      float pp = p[bi];
      for (int off = 32; off; off >>= 1) pp += __shfl_down(pp, off, 64);
      if (lane == 0) Qm[(size_t)(b0 + bi) * AA + a] = pp + bQ[a];
    }
  }
}

// ---------------------------------------------------------------------------
// K4: qk[b,d] = Q[b,:]·WKT[d,:]   (WKT = WK^T, 768x256)  grid (24, 32)
// reduction len 256 = 64 lanes x 1 float4
// ---------------------------------------------------------------------------
__global__ void k_qk(const float* __restrict__ Qm, const float* __restrict__ WKT,
                     float* __restrict__ qk) {
  int d0 = blockIdx.x * 32;
  int b0 = blockIdx.y * 3;
  int lane = threadIdx.x & 63, wave = threadIdx.x >> 6;
  float4 x[3];
#pragma unroll
  for (int bi = 0; bi < 3; ++bi)
    x[bi] = ((const float4*)(Qm + (size_t)(b0 + bi) * AA))[lane];
  for (int i = 0; i < 8; ++i) {
    int d = d0 + wave * 8 + i;
    float4 w = ((const float4*)(WKT + (size_t)d * AA))[lane];
    float p[3];
#pragma unroll
    for (int bi = 0; bi < 3; ++bi) p[bi] = dot4(w, x[bi]);
#pragma unroll
    for (int bi = 0; bi < 3; ++bi) {
      float pp = p[bi];
      for (int off = 32; off; off >>= 1) pp += __shfl_down(pp, off, 64);
      if (lane == 0) qk[(size_t)(b0 + bi) * DD + d] = pp;
    }
  }
}

// ---------------------------------------------------------------------------
// K5: v[b,d] = (1/16) * qk[b,:]·WrT[d,:]   (WrT = Wr^T)   grid (24, 32)
// ---------------------------------------------------------------------------
__global__ void k_v(const float* __restrict__ qk, const float* __restrict__ WrT,
                    float* __restrict__ vv) {
  int d0 = blockIdx.x * 32;
  int b0 = blockIdx.y * 3;
  int lane = threadIdx.x & 63, wave = threadIdx.x >> 6;
  float4 x[3][3];
#pragma unroll
  for (int bi = 0; bi < 3; ++bi)
#pragma unroll
    for (int jj = 0; jj < 3; ++jj)
      x[bi][jj] = ((const float4*)(qk + (size_t)(b0 + bi) * DD))[lane + 64 * jj];
  for (int i = 0; i < 8; ++i) {
    int d = d0 + wave * 8 + i;
    const float4* w4 = (const float4*)(WrT + (size_t)d * DD);
    float p[3] = {0.f, 0.f, 0.f};
#pragma unroll
    for (int jj = 0; jj < 3; ++jj) {
      float4 w = w4[lane + 64 * jj];
#pragma unroll
      for (int bi = 0; bi < 3; ++bi) p[bi] += dot4(w, x[bi][jj]);
    }
#pragma unroll
    for (int bi = 0; bi < 3; ++bi) {
      float pp = p[bi];
      for (int off = 32; off; off >>= 1) pp += __shfl_down(pp, off, 64);
      if (lane == 0) vv[(size_t)(b0 + bi) * DD + d] = pp * (1.f / 16.f);
    }
  }
}

// ---------------------------------------------------------------------------
// K6: scores[b,h] = hist[b,h,:]·v[b,:]   (wave-split-K; 20 h per block)
// ---------------------------------------------------------------------------
__global__ void k_scores(const float* __restrict__ hist, const float* __restrict__ vv,
                         float* __restrict__ sc) {
  int b = blockIdx.x, hg = blockIdx.y;
  int lane = threadIdx.x & 63, wave = threadIdx.x >> 6;
  float4 v[3];
  const float4* vb = (const float4*)(vv + (size_t)b * DD);
#pragma unroll
  for (int jj = 0; jj < 3; ++jj) v[jj] = vb[lane + 64 * jj];
  const float* hb = hist + (size_t)b * HH * DD;
  for (int i = 0; i < 5; ++i) {
    int h = hg * 20 + wave * 5 + i;
    const float4* r = (const float4*)(hb + (size_t)h * DD);
    float p = 0.f;
#pragma unroll
    for (int jj = 0; jj < 3; ++jj) p += dot4(r[lane + 64 * jj], v[jj]);
    for (int off = 32; off; off >>= 1) p += __shfl_down(p, off, 64);
    if (lane == 0) sc[b * 128 + h] = p;
  }
}

// ---------------------------------------------------------------------------
// K7: softmax over h (once per block in LDS) + weighted hist sum
// h-loop batched 4-wide so 4 loads stay in flight
// ---------------------------------------------------------------------------
__global__ void k_wsum(const float* __restrict__ hist, const float* __restrict__ sc,
                       float* __restrict__ wsum) {
  int b = blockIdx.x;
  int e = blockIdx.y * 256 + threadIdx.x;
  __shared__ float sal[HH];
  __shared__ float s_inv;
  if (threadIdx.x < HH) sal[threadIdx.x] = sc[b * 128 + threadIdx.x];
  __syncthreads();
  if (threadIdx.x == 0) {
    float m = -1e30f;
    for (int h = 0; h < HH; ++h) m = fmaxf(m, sal[h]);
    float s = 0.f;
    for (int h = 0; h < HH; ++h) { float ex = __expf(sal[h] - m); sal[h] = ex; s += ex; }
    s_inv = 1.f / s;
  }
  __syncthreads();
  float inv = s_inv;
  float acc = 0.f;
  const float* hb = hist + (size_t)b * HH * DD + e;
  for (int h = 0; h < HH; h += 4) {  // 100 % 4 == 0
    float v0 = hb[(size_t)(h + 0) * DD];
    float v1 = hb[(size_t)(h + 1) * DD];
    float v2 = hb[(size_t)(h + 2) * DD];
    float v3 = hb[(size_t)(h + 3) * DD];
    acc += sal[h + 0] * v0 + sal[h + 1] * v1 + sal[h + 2] * v2 + sal[h + 3] * v3;
  }
  wsum[(size_t)b * DD + e] = acc * inv;
}

// ---------------------------------------------------------------------------
// K8: orow[b,d] = nl[b,d] + wsum[b,:]·W_r[d,:]   grid (24, 32)
// ---------------------------------------------------------------------------
__global__ void k_orow(const float* __restrict__ wsum, const float* __restrict__ Wr,
                       const float* __restrict__ nl, float* __restrict__ orow) {
  int d0 = blockIdx.x * 32;
  int b0 = blockIdx.y * 3;
  int lane = threadIdx.x & 63, wave = threadIdx.x >> 6;
  float4 x[3][3];
#pragma unroll
  for (int bi = 0; bi < 3; ++bi)
#pragma unroll
    for (int jj = 0; jj < 3; ++jj)
      x[bi][jj] = ((const float4*)(wsum + (size_t)(b0 + bi) * DD))[lane + 64 * jj];
  for (int i = 0; i < 8; ++i) {
    int d = d0 + wave * 8 + i;
    const float4* w4 = (const float4*)(Wr + (size_t)d * DD);
    float p[3] = {0.f, 0.f, 0.f};
#pragma unroll
    for (int jj = 0; jj < 3; ++jj) {
      float4 w = w4[lane + 64 * jj];
#pragma unroll
      for (int bi = 0; bi < 3; ++bi) p[bi] += dot4(w, x[bi][jj]);
    }
#pragma unroll
    for (int bi = 0; bi < 3; ++bi) {
      float pp = p[bi];
      for (int off = 32; off; off >>= 1) pp += __shfl_down(pp, off, 64);
      if (lane == 0)
        orow[(size_t)(b0 + bi) * DD + d] = pp + nl[(size_t)(b0 + bi) * DD + d];
    }
  }
}

// ---------------------------------------------------------------------------
// K9: out[b,n,d] = orow[b,d]  — float4 per thread, fully coalesced
// ---------------------------------------------------------------------------
__global__ void k_write(const float* __restrict__ orow, float* __restrict__ out) {
  size_t t = (size_t)blockIdx.x * 256 + threadIdx.x;  // 2,359,296 threads
  int d4 = (int)(t % (DD / 4));
  int bn = (int)(t / (DD / 4));
  int b = bn >> 7;
  float4 v = *(const float4*)(orow + (size_t)b * DD + d4 * 4);
  *(float4*)(out + (size_t)bn * DD + d4 * 4) = v;
}

// ---------------------------------------------------------------------------
extern "C" void kernel_launch(void* const* d_in, const int* in_sizes, int n_in,
                              void* d_out, int out_size, void* d_ws, size_t ws_size,
                              hipStream_t stream) {
  const float *hist = nullptr, *Wl = nullptr, *Wr = nullptr, *WK = nullptr,
              *WQ = nullptr, *bl = nullptr, *bQ = nullptr;
  int seenDxD = 0, seenAxD = 0;
  for (int i = 0; i < n_in; ++i) {
    int s = in_sizes[i];
    const float* p = (const float*)d_in[i];
    if (s == BB * HH * DD) hist = p;
    else if (s == BB * NN * DD) { /* candidate — unused */ }
    else if (s == DD * DD) { if (seenDxD++ == 0) Wl = p; else Wr = p; }
    else if (s == AA * DD) { if (seenAxD++ == 0) WK = p; else WQ = p; }
    else if (s == DD) bl = p;
    else if (s == AA) bQ = p;
  }

  float* ws = (float*)d_ws;
  float* neighp = ws + 0;         // 8*96*768 = 589824
  float* WrT    = ws + 589824;    // 589824
  float* WKT    = ws + 1179648;   // 196608
  float* nl     = ws + 1376256;   // 73728
  float* u0     = ws + 1449984;   // 73728
  float* Qm     = ws + 1523712;   // 24576
  float* qk     = ws + 1548288;   // 73728
  float* vv     = ws + 1622016;   // 73728
  float* sc     = ws + 1695744;   // 12288
  float* wsum   = ws + 1708032;   // 73728
  float* orow   = ws + 1781760;   // 73728  -> total ~7.4 MB
  float* out = (float*)d_out;

  t_trans <<<dim3(24, 24), dim3(256), 0, stream>>>(Wr, WrT, DD, DD);
  t_trans <<<dim3(24, 8),  dim3(256), 0, stream>>>(WK, WKT, AA, DD);
  k_neigh <<<dim3(BB, 8),  dim3(192), 0, stream>>>(hist, neighp);
  k_nl_u0 <<<dim3(24, 32), dim3(256), 0, stream>>>(neighp, hist, Wl, bl, Wr, nl, u0);
  k_q     <<<dim3(8, 32),  dim3(256), 0, stream>>>(u0, WQ, bQ, Qm);
  k_qk    <<<dim3(24, 32), dim3(256), 0, stream>>>(Qm, WKT, qk);
  k_v     <<<dim3(24, 32), dim3(256), 0, stream>>>(qk, WrT, vv);
  k_scores<<<dim3(BB, 5),  dim3(256), 0, stream>>>(hist, vv, sc);
  k_wsum  <<<dim3(BB, 3),  dim3(256), 0, stream>>>(hist, sc, wsum);
  k_orow  <<<dim3(24, 32), dim3(256), 0, stream>>>(wsum, Wr, nl, orow);
  k_write <<<dim3(9216),   dim3(256), 0, stream>>>(orow, out);
}